// Round 8
// baseline (165.506 us; speedup 1.0000x reference)
//
#include <hip/hip_runtime.h>
#include <hip/hip_fp16.h>
#include <math.h>
#include <string.h>

#define LN_ZERO (-100000000000.0f)

constexpr int F_ = 250000;
constexpr int V_ = 250000;
constexpr int E_ = 1000000;      // F_ * 4

// Multisplit parameters
constexpr int NBLK  = 64;            // P2 blocks (edge slices)
constexpr int PARTS = 64;            // variable partitions
constexpr int BINS  = 3907;          // ceil(V/PARTS); 64*3907 = 250048 >= V
constexpr int CAP   = 352;           // bucket capacity (+7 sigma of 244)
constexpr int SLICE = E_ / NBLK;     // 15625
static_assert(NBLK * SLICE == E_, "");
static_assert(PARTS * BINS >= V_, "");

static __device__ inline unsigned pack_h2(float x, float y) {
    __half2 h = __floats2half2_rn(x, y);
    unsigned u; memcpy(&u, &h, 4); return u;
}
static __device__ inline float2 unpack_h2(unsigned u) {
    __half2 h; memcpy(&h, &u, 4); return __half22float2(h);
}

// ---------------------------------------------------------------------------
// MS1 (P2 of crossing #1) + fused potmask compression.
// Block b reads edge slice [b*SLICE, (b+1)*SLICE) once, routes (v_local, msg)
// pairs into per-(b,partition) buckets via LDS cursors. No global atomics
// except the ~never-taken overflow fallback.
__global__ __launch_bounds__(1024)
void k_ms1(const int* __restrict__ edge_v,
           const float2* __restrict__ msgs,
           const int4* __restrict__ potmask4,
           unsigned short* __restrict__ potbits,
           uint2* __restrict__ buckets,
           int* __restrict__ counts,
           __half2* __restrict__ accP) {
    __shared__ int cur[PARTS];
    int b = blockIdx.x, tid = threadIdx.x;
    if (tid < PARTS) cur[tid] = 0;
    __syncthreads();

    // fused prep: potbits
    for (int f = b * 1024 + tid; f < F_; f += NBLK * 1024) {
        unsigned int bits = 0;
#pragma unroll
        for (int j = 0; j < 4; ++j) {
            int4 pm = potmask4[4 * f + j];
            bits |= (pm.x == 1 ? 1u : 0u) << (4 * j + 0);
            bits |= (pm.y == 1 ? 1u : 0u) << (4 * j + 1);
            bits |= (pm.z == 1 ? 1u : 0u) << (4 * j + 2);
            bits |= (pm.w == 1 ? 1u : 0u) << (4 * j + 3);
        }
        potbits[f] = (unsigned short)bits;
    }

    int ebase = b * SLICE;
    for (int i = tid; i < SLICE; i += 1024) {
        int e = ebase + i;
        int v = edge_v[e];
        int p = v / BINS;
        float2 m = msgs[e];
        int pos = atomicAdd(&cur[p], 1);
        if (pos < CAP)
            buckets[((size_t)b * PARTS + p) * CAP + pos] =
                make_uint2((unsigned)(v - p * BINS), pack_h2(m.x, m.y));
        else
            unsafeAtomicAdd(&accP[v], __floats2half2_rn(m.x, m.y));
    }
    __syncthreads();
    if (tid < PARTS) counts[b * PARTS + tid] = min(cur[tid], CAP);
}

// ---------------------------------------------------------------------------
// ACC1 (P3 of crossing #1): block p accumulates its partition in LDS,
// clamps, writes accP[v] as CLAMPED half2.
__global__ __launch_bounds__(1024)
void k_acc1(const uint2* __restrict__ buckets,
            const int* __restrict__ counts,
            const unsigned short* __restrict__ vb_mask2,
            __half2* __restrict__ accP) {
    __shared__ float2 acc[BINS];    // 31256 B
    int p = blockIdx.x, tid = threadIdx.x;
    int vbase = p * BINS;
    int nb = min(BINS, V_ - vbase);
    for (int j = tid; j < BINS; j += 1024)
        acc[j] = (j < nb) ? __half22float2(accP[vbase + j]) : make_float2(0.f, 0.f);
    __syncthreads();
    for (int b = 0; b < NBLK; ++b) {
        int n = counts[b * PARTS + p];
        const uint2* seg = buckets + ((size_t)b * PARTS + p) * CAP;
        for (int i = tid; i < n; i += 1024) {
            uint2 pr = seg[i];
            float2 mv = unpack_h2(pr.y);
            atomicAdd(&acc[pr.x].x, mv.x);
            atomicAdd(&acc[pr.x].y, mv.y);
        }
    }
    __syncthreads();
    for (int j = tid; j < nb; j += 1024) {
        int v = vbase + j;
        unsigned short vbm = vb_mask2[v];
        float b0 = fmaxf((vbm & 0xff) ? LN_ZERO : acc[j].x, LN_ZERO);
        float b1 = fmaxf((vbm >> 8)   ? LN_ZERO : acc[j].y, LN_ZERO);
        accP[v] = __floats2half2_rn(b0, b1);
    }
}

// ---------------------------------------------------------------------------
// Edge-parallel factor messages: 4 threads per factor (d = e & 3).
// accP is pre-clamped half2 -> no vb_mask gather, no atomics.
__global__ void k_factor_msgs(const float2* __restrict__ msgs,
                              const int* __restrict__ edge_v,
                              const __half2* __restrict__ accP,   // clamped prv
                              const float4* __restrict__ pot4,
                              const unsigned short* __restrict__ potbits,
                              const unsigned short* __restrict__ f2v_mask2,
                              const unsigned short* __restrict__ v2f_mask2,
                              float2* __restrict__ out_f2v) {
    int e = blockIdx.x * blockDim.x + threadIdx.x;
    if (e >= E_) return;
    int d = e & 3;
    int v = edge_v[e];

    float2 s = __half22float2(accP[v]);
    float2 m = msgs[e];
    unsigned short vm = v2f_mask2[e];
    float wx = fmaxf((vm & 0xff) ? LN_ZERO : (s.x - m.x), LN_ZERO);
    float wy = fmaxf((vm >> 8)   ? LN_ZERO : (s.y - m.y), LN_ZERO);

    float w0x = __shfl(wx, 0, 4), w0y = __shfl(wy, 0, 4);
    float w1x = __shfl(wx, 1, 4), w1y = __shfl(wy, 1, 4);
    float w2x = __shfl(wx, 2, 4), w2y = __shfl(wy, 2, 4);
    float w3x = __shfl(wx, 3, 4), w3y = __shfl(wy, 3, 4);

    // states s = 4d+k: bit0(s)=d>>1, bit1(s)=d&1, bit2(s)=k>>1, bit3(s)=k&1
    float4 p = pot4[e];
    unsigned int pb = potbits[e >> 2] >> (4 * d);
    float A = ((d >> 1) ? w0y : w0x) + ((d & 1) ? w1y : w1x);
    float fb0 = p.x + A + w2x + w3x;
    float fb1 = p.y + A + w2x + w3y;
    float fb2 = p.z + A + w2y + w3x;
    float fb3 = p.w + A + w2y + w3y;
    fb0 = fmaxf((pb & 1u) ? LN_ZERO : fb0, LN_ZERO);
    fb1 = fmaxf((pb & 2u) ? LN_ZERO : fb1, LN_ZERO);
    fb2 = fmaxf((pb & 4u) ? LN_ZERO : fb2, LN_ZERO);
    fb3 = fmaxf((pb & 8u) ? LN_ZERO : fb3, LN_ZERO);

    float mk2_0 = fmaxf(fb0, fb1);
    float mk2_1 = fmaxf(fb2, fb3);
    float mk3_0 = fmaxf(fb0, fb2);
    float mk3_1 = fmaxf(fb1, fb3);
    float mloc  = fmaxf(mk2_0, mk2_1);

#pragma unroll
    for (int off = 1; off < 4; off <<= 1) {
        mk2_0 = fmaxf(mk2_0, __shfl_xor(mk2_0, off, 4));
        mk2_1 = fmaxf(mk2_1, __shfl_xor(mk2_1, off, 4));
        mk3_0 = fmaxf(mk3_0, __shfl_xor(mk3_0, off, 4));
        mk3_1 = fmaxf(mk3_1, __shfl_xor(mk3_1, off, 4));
    }
    float ml0 = __shfl(mloc, 0, 4);
    float ml1 = __shfl(mloc, 1, 4);
    float ml2 = __shfl(mloc, 2, 4);
    float ml3 = __shfl(mloc, 3, 4);

    float mm0, mm1;
    if (d == 0)      { mm0 = fmaxf(ml0, ml1); mm1 = fmaxf(ml2, ml3); }
    else if (d == 1) { mm0 = fmaxf(ml0, ml2); mm1 = fmaxf(ml1, ml3); }
    else if (d == 2) { mm0 = mk2_0;           mm1 = mk2_1; }
    else             { mm0 = mk3_0;           mm1 = mk3_1; }

    float raw0 = mm0 - wx;
    float raw1 = mm1 - wy;
    float mx = fmaxf(raw0, raw1);
    float lse = mx + logf(expf(raw0 - mx) + expf(raw1 - mx));
    unsigned short fm = f2v_mask2[e];
    float o0 = fmaxf((fm & 0xff) ? LN_ZERO : (raw0 - lse), LN_ZERO);
    float o1 = fmaxf((fm >> 8)   ? LN_ZERO : (raw1 - lse), LN_ZERO);
    out_f2v[e] = make_float2(o0, o1);
}

// ---------------------------------------------------------------------------
// MS2 (P2 of crossing #2): route (v_local, f2v) pairs into buckets.
// Overflow -> float atomics into raw out_vb (zeroed).
__global__ __launch_bounds__(1024)
void k_ms2(const int* __restrict__ edge_v,
           const float2* __restrict__ f2v,
           uint2* __restrict__ buckets,
           int* __restrict__ counts,
           float* __restrict__ out_vb_raw) {
    __shared__ int cur[PARTS];
    int b = blockIdx.x, tid = threadIdx.x;
    if (tid < PARTS) cur[tid] = 0;
    __syncthreads();
    int ebase = b * SLICE;
    for (int i = tid; i < SLICE; i += 1024) {
        int e = ebase + i;
        int v = edge_v[e];
        int p = v / BINS;
        float2 g = f2v[e];
        int pos = atomicAdd(&cur[p], 1);
        if (pos < CAP)
            buckets[((size_t)b * PARTS + p) * CAP + pos] =
                make_uint2((unsigned)(v - p * BINS), pack_h2(g.x, g.y));
        else {
            atomicAdd(&out_vb_raw[2 * v + 0], g.x);
            atomicAdd(&out_vb_raw[2 * v + 1], g.y);
        }
    }
    __syncthreads();
    if (tid < PARTS) counts[b * PARTS + tid] = min(cur[tid], CAP);
}

// ---------------------------------------------------------------------------
// ACC2 (P3 of crossing #2): accumulate -> clamp -> out_vb (f32 output).
__global__ __launch_bounds__(1024)
void k_acc2(const uint2* __restrict__ buckets,
            const int* __restrict__ counts,
            const unsigned short* __restrict__ vb_mask2,
            float2* __restrict__ out_vb) {
    __shared__ float2 acc[BINS];
    int p = blockIdx.x, tid = threadIdx.x;
    int vbase = p * BINS;
    int nb = min(BINS, V_ - vbase);
    for (int j = tid; j < BINS; j += 1024)
        acc[j] = (j < nb) ? out_vb[vbase + j] : make_float2(0.f, 0.f);
    __syncthreads();
    for (int b = 0; b < NBLK; ++b) {
        int n = counts[b * PARTS + p];
        const uint2* seg = buckets + ((size_t)b * PARTS + p) * CAP;
        for (int i = tid; i < n; i += 1024) {
            uint2 pr = seg[i];
            float2 mv = unpack_h2(pr.y);
            atomicAdd(&acc[pr.x].x, mv.x);
            atomicAdd(&acc[pr.x].y, mv.y);
        }
    }
    __syncthreads();
    for (int j = tid; j < nb; j += 1024) {
        int v = vbase + j;
        unsigned short vbm = vb_mask2[v];
        float b0 = fmaxf((vbm & 0xff) ? LN_ZERO : acc[j].x, LN_ZERO);
        float b1 = fmaxf((vbm >> 8)   ? LN_ZERO : acc[j].y, LN_ZERO);
        out_vb[v] = make_float2(b0, b1);
    }
}

// ---------------------------------------------------------------------------
// Edge-parallel factor beliefs: each thread writes one float4 of [F,16].
__global__ void k_factor_beliefs(const float2* __restrict__ new_f2v,
                                 const float2* __restrict__ vb,      // clamped new
                                 const int* __restrict__ edge_v,
                                 const float4* __restrict__ pot4,
                                 const unsigned short* __restrict__ potbits,
                                 const unsigned short* __restrict__ v2f_mask2,
                                 float4* __restrict__ out_fb4) {
    int e = blockIdx.x * blockDim.x + threadIdx.x;
    if (e >= E_) return;
    int d = e & 3;

    float2 b = vb[edge_v[e]];
    float2 g = new_f2v[e];
    unsigned short vm = v2f_mask2[e];
    float wx = fmaxf((vm & 0xff) ? LN_ZERO : (b.x - g.x), LN_ZERO);
    float wy = fmaxf((vm >> 8)   ? LN_ZERO : (b.y - g.y), LN_ZERO);

    float w0x = __shfl(wx, 0, 4), w0y = __shfl(wy, 0, 4);
    float w1x = __shfl(wx, 1, 4), w1y = __shfl(wy, 1, 4);
    float w2x = __shfl(wx, 2, 4), w2y = __shfl(wy, 2, 4);
    float w3x = __shfl(wx, 3, 4), w3y = __shfl(wy, 3, 4);

    float4 p = pot4[e];
    unsigned int pb = potbits[e >> 2] >> (4 * d);
    float A = ((d >> 1) ? w0y : w0x) + ((d & 1) ? w1y : w1x);
    float o0 = fmaxf((pb & 1u) ? LN_ZERO : (p.x + A + w2x + w3x), LN_ZERO);
    float o1 = fmaxf((pb & 2u) ? LN_ZERO : (p.y + A + w2x + w3y), LN_ZERO);
    float o2 = fmaxf((pb & 4u) ? LN_ZERO : (p.z + A + w2y + w3x), LN_ZERO);
    float o3 = fmaxf((pb & 8u) ? LN_ZERO : (p.w + A + w2y + w3y), LN_ZERO);
    out_fb4[e] = make_float4(o0, o1, o2, o3);
}

// ---------------------------------------------------------------------------
extern "C" void kernel_launch(void* const* d_in, const int* in_sizes, int n_in,
                              void* d_out, int out_size, void* d_ws, size_t ws_size,
                              hipStream_t stream) {
    const float* msgs     = (const float*)d_in[0];           // [E, C]
    const float* pot      = (const float*)d_in[1];           // [F, 16]
    const int*   edge_idx = (const int*)d_in[2];             // [2, E]
    const int*   pot_mask = (const int*)d_in[5];             // [F, 16] int32
    const unsigned char* f2v_mask = (const unsigned char*)d_in[6];  // [E, C]
    const unsigned char* v2f_mask = (const unsigned char*)d_in[7];  // [E, C]
    const unsigned char* vb_mask  = (const unsigned char*)d_in[8];  // [V, C]

    const int* edge_v = edge_idx + E_;

    float* out      = (float*)d_out;
    float* out_f2v  = out;                          // E*C floats
    float* out_vb   = out + (size_t)E_ * 2;         // V*C floats
    float* out_fb   = out_vb + (size_t)V_ * 2;      // F*16 floats

    // workspace layout:
    //   buckets uint2[NBLK*PARTS*CAP]  = 11,534,336 B
    //   counts  int[NBLK*PARTS]        =     16,384 B
    //   accP    half2[V]               =  1,000,000 B
    //   potbits ushort[F]              =    500,000 B
    //   total ~= 13.05 MB
    uint2* buckets = (uint2*)d_ws;
    int* counts = (int*)(buckets + (size_t)NBLK * PARTS * CAP);
    __half2* accP = (__half2*)(counts + NBLK * PARTS);
    unsigned short* potbits = (unsigned short*)(accP + V_);

    hipMemsetAsync(accP, 0, (size_t)V_ * sizeof(__half2), stream);
    hipMemsetAsync(out_vb, 0, (size_t)V_ * 2 * sizeof(float), stream);

    const int B = 256;
    dim3 gE((E_ + B - 1) / B);

    // crossing #1: msgs -> vb_prv (clamped half2 in accP)
    k_ms1<<<NBLK, 1024, 0, stream>>>(edge_v, (const float2*)msgs,
                                     (const int4*)pot_mask, potbits,
                                     buckets, counts, accP);
    k_acc1<<<PARTS, 1024, 0, stream>>>(buckets, counts,
                                       (const unsigned short*)vb_mask, accP);

    // factor messages (atomic-free)
    k_factor_msgs<<<gE, B, 0, stream>>>((const float2*)msgs, edge_v, accP,
                                        (const float4*)pot, potbits,
                                        (const unsigned short*)f2v_mask,
                                        (const unsigned short*)v2f_mask,
                                        (float2*)out_f2v);

    // crossing #2: new_f2v -> vb_new (clamped f32 in out_vb)
    k_ms2<<<NBLK, 1024, 0, stream>>>(edge_v, (const float2*)out_f2v,
                                     buckets, counts, out_vb);
    k_acc2<<<PARTS, 1024, 0, stream>>>(buckets, counts,
                                       (const unsigned short*)vb_mask,
                                       (float2*)out_vb);

    // factor beliefs
    k_factor_beliefs<<<gE, B, 0, stream>>>((const float2*)out_f2v,
                                           (const float2*)out_vb, edge_v,
                                           (const float4*)pot, potbits,
                                           (const unsigned short*)v2f_mask,
                                           (float4*)out_fb);
}

// Round 9
// 89.981 us; speedup vs baseline: 1.8393x; 1.8393x over previous
//
#include <hip/hip_runtime.h>
#include <hip/hip_fp16.h>
#include <math.h>
#include <string.h>

#define LN_ZERO (-100000000000.0f)

constexpr int F_ = 250000;
constexpr int V_ = 250000;
constexpr int E_ = 1000000;      // F_ * 4

// Multisplit parameters: full-chip grids for BOTH phases.
constexpr int NBLK  = 256;                       // edge slices (ms grid)
constexpr int PARTS = 256;                       // variable partitions (acc grid)
constexpr int BINS  = 977;                       // ceil(V/PARTS); 256*977 >= V
constexpr int CAP   = 30;                        // per-(slice,part) bucket cap
constexpr int SLICE = (E_ + NBLK - 1) / NBLK;    // 3907
static_assert(PARTS * BINS >= V_, "");
static_assert((size_t)NBLK * PARTS * CAP * 8 <= (size_t)F_ * 16 * 4, "buckets fit in out_fb");

static __device__ inline unsigned pack_h2(float x, float y) {
    __half2 h = __floats2half2_rn(x, y);
    unsigned u; memcpy(&u, &h, 4); return u;
}
static __device__ inline float2 unpack_h2(unsigned u) {
    __half2 h; memcpy(&h, &u, 4); return __half22float2(h);
}

// ---------------------------------------------------------------------------
// MS1: slice b routes (v_local, msg-half2) pairs into per-(b,part) buckets via
// LDS cursors. Fused potbits compression. Overflow -> pk-f16 atomic (rare).
__global__ __launch_bounds__(1024)
void k_ms1(const int* __restrict__ edge_v,
           const float2* __restrict__ msgs,
           const int4* __restrict__ potmask4,
           unsigned short* __restrict__ potbits,
           uint2* __restrict__ buckets,
           int* __restrict__ counts,
           __half2* __restrict__ accP) {
    __shared__ int cur[PARTS];
    int b = blockIdx.x, tid = threadIdx.x;
    if (tid < PARTS) cur[tid] = 0;
    __syncthreads();

    // fused prep: potbits (one pass, 256*1024 threads cover F_)
    int f = b * 1024 + tid;
    if (f < F_) {
        unsigned int bits = 0;
#pragma unroll
        for (int j = 0; j < 4; ++j) {
            int4 pm = potmask4[4 * f + j];
            bits |= (pm.x == 1 ? 1u : 0u) << (4 * j + 0);
            bits |= (pm.y == 1 ? 1u : 0u) << (4 * j + 1);
            bits |= (pm.z == 1 ? 1u : 0u) << (4 * j + 2);
            bits |= (pm.w == 1 ? 1u : 0u) << (4 * j + 3);
        }
        potbits[f] = (unsigned short)bits;
    }

    int ebase = b * SLICE;
    int eend = min(ebase + SLICE, E_);
    for (int e = ebase + tid; e < eend; e += 1024) {
        int v = edge_v[e];
        int p = v / BINS;
        float2 m = msgs[e];
        int pos = atomicAdd(&cur[p], 1);
        if (pos < CAP)
            buckets[((size_t)b * PARTS + p) * CAP + pos] =
                make_uint2((unsigned)(v - p * BINS), pack_h2(m.x, m.y));
        else
            unsafeAtomicAdd(&accP[v], __floats2half2_rn(m.x, m.y));
    }
    __syncthreads();
    if (tid < PARTS) counts[b * PARTS + tid] = min(cur[tid], CAP);
}

// ---------------------------------------------------------------------------
// ACC1: block p = one variable partition. LDS prefix-scan of the 256 slice
// counts, then ALL threads walk the concatenated items (binary search for the
// segment). LDS float atomics accumulate; clamp; write accP as clamped half2.
__global__ __launch_bounds__(1024)
void k_acc1(const uint2* __restrict__ buckets,
            const int* __restrict__ counts,
            const unsigned short* __restrict__ vb_mask2,
            __half2* __restrict__ accP) {
    __shared__ float2 acc[BINS];
    __shared__ int pre[NBLK + 1];
    int p = blockIdx.x, tid = threadIdx.x;
    int vbase = p * BINS;
    int nb = min(BINS, V_ - vbase);

    for (int j = tid; j < BINS; j += 1024)
        acc[j] = (j < nb) ? __half22float2(accP[vbase + j]) : make_float2(0.f, 0.f);
    if (tid < NBLK) pre[tid + 1] = counts[tid * PARTS + p];
    if (tid == 0) pre[0] = 0;
    __syncthreads();
#pragma unroll
    for (int off = 1; off < NBLK; off <<= 1) {
        int t = (tid >= off && tid < NBLK) ? pre[tid + 1 - off] : 0;
        __syncthreads();
        if (tid < NBLK) pre[tid + 1] += t;
        __syncthreads();
    }
    int T = pre[NBLK];
    for (int i = tid; i < T; i += 1024) {
        int lo = 0, hi = NBLK;
        while (hi - lo > 1) { int mid = (lo + hi) >> 1; if (pre[mid] <= i) lo = mid; else hi = mid; }
        uint2 pr = buckets[((size_t)lo * PARTS + p) * CAP + (i - pre[lo])];
        float2 mv = unpack_h2(pr.y);
        atomicAdd(&acc[pr.x].x, mv.x);
        atomicAdd(&acc[pr.x].y, mv.y);
    }
    __syncthreads();
    for (int j = tid; j < nb; j += 1024) {
        int v = vbase + j;
        unsigned short vbm = vb_mask2[v];
        float b0 = fmaxf((vbm & 0xff) ? LN_ZERO : acc[j].x, LN_ZERO);
        float b1 = fmaxf((vbm >> 8)   ? LN_ZERO : acc[j].y, LN_ZERO);
        accP[v] = __floats2half2_rn(b0, b1);
    }
}

// ---------------------------------------------------------------------------
// Edge-parallel factor messages (atomic-free): 4 threads per factor.
__global__ void k_factor_msgs(const float2* __restrict__ msgs,
                              const int* __restrict__ edge_v,
                              const __half2* __restrict__ accP,   // clamped prv
                              const float4* __restrict__ pot4,
                              const unsigned short* __restrict__ potbits,
                              const unsigned short* __restrict__ f2v_mask2,
                              const unsigned short* __restrict__ v2f_mask2,
                              float2* __restrict__ out_f2v) {
    int e = blockIdx.x * blockDim.x + threadIdx.x;
    if (e >= E_) return;
    int d = e & 3;
    int v = edge_v[e];

    float2 s = __half22float2(accP[v]);
    float2 m = msgs[e];
    unsigned short vm = v2f_mask2[e];
    float wx = fmaxf((vm & 0xff) ? LN_ZERO : (s.x - m.x), LN_ZERO);
    float wy = fmaxf((vm >> 8)   ? LN_ZERO : (s.y - m.y), LN_ZERO);

    float w0x = __shfl(wx, 0, 4), w0y = __shfl(wy, 0, 4);
    float w1x = __shfl(wx, 1, 4), w1y = __shfl(wy, 1, 4);
    float w2x = __shfl(wx, 2, 4), w2y = __shfl(wy, 2, 4);
    float w3x = __shfl(wx, 3, 4), w3y = __shfl(wy, 3, 4);

    // states s = 4d+k: bit0(s)=d>>1, bit1(s)=d&1, bit2(s)=k>>1, bit3(s)=k&1
    float4 p = pot4[e];
    unsigned int pb = potbits[e >> 2] >> (4 * d);
    float A = ((d >> 1) ? w0y : w0x) + ((d & 1) ? w1y : w1x);
    float fb0 = p.x + A + w2x + w3x;
    float fb1 = p.y + A + w2x + w3y;
    float fb2 = p.z + A + w2y + w3x;
    float fb3 = p.w + A + w2y + w3y;
    fb0 = fmaxf((pb & 1u) ? LN_ZERO : fb0, LN_ZERO);
    fb1 = fmaxf((pb & 2u) ? LN_ZERO : fb1, LN_ZERO);
    fb2 = fmaxf((pb & 4u) ? LN_ZERO : fb2, LN_ZERO);
    fb3 = fmaxf((pb & 8u) ? LN_ZERO : fb3, LN_ZERO);

    float mk2_0 = fmaxf(fb0, fb1);
    float mk2_1 = fmaxf(fb2, fb3);
    float mk3_0 = fmaxf(fb0, fb2);
    float mk3_1 = fmaxf(fb1, fb3);
    float mloc  = fmaxf(mk2_0, mk2_1);

#pragma unroll
    for (int off = 1; off < 4; off <<= 1) {
        mk2_0 = fmaxf(mk2_0, __shfl_xor(mk2_0, off, 4));
        mk2_1 = fmaxf(mk2_1, __shfl_xor(mk2_1, off, 4));
        mk3_0 = fmaxf(mk3_0, __shfl_xor(mk3_0, off, 4));
        mk3_1 = fmaxf(mk3_1, __shfl_xor(mk3_1, off, 4));
    }
    float ml0 = __shfl(mloc, 0, 4);
    float ml1 = __shfl(mloc, 1, 4);
    float ml2 = __shfl(mloc, 2, 4);
    float ml3 = __shfl(mloc, 3, 4);

    float mm0, mm1;
    if (d == 0)      { mm0 = fmaxf(ml0, ml1); mm1 = fmaxf(ml2, ml3); }
    else if (d == 1) { mm0 = fmaxf(ml0, ml2); mm1 = fmaxf(ml1, ml3); }
    else if (d == 2) { mm0 = mk2_0;           mm1 = mk2_1; }
    else             { mm0 = mk3_0;           mm1 = mk3_1; }

    float raw0 = mm0 - wx;
    float raw1 = mm1 - wy;
    float mx = fmaxf(raw0, raw1);
    float lse = mx + logf(expf(raw0 - mx) + expf(raw1 - mx));
    unsigned short fm = f2v_mask2[e];
    float o0 = fmaxf((fm & 0xff) ? LN_ZERO : (raw0 - lse), LN_ZERO);
    float o1 = fmaxf((fm >> 8)   ? LN_ZERO : (raw1 - lse), LN_ZERO);
    out_f2v[e] = make_float2(o0, o1);
}

// ---------------------------------------------------------------------------
// MS2: route (v_local, f2v-half2) pairs. Overflow -> f32 atomics into raw out_vb.
__global__ __launch_bounds__(1024)
void k_ms2(const int* __restrict__ edge_v,
           const float2* __restrict__ f2v,
           uint2* __restrict__ buckets,
           int* __restrict__ counts,
           float* __restrict__ out_vb_raw) {
    __shared__ int cur[PARTS];
    int b = blockIdx.x, tid = threadIdx.x;
    if (tid < PARTS) cur[tid] = 0;
    __syncthreads();
    int ebase = b * SLICE;
    int eend = min(ebase + SLICE, E_);
    for (int e = ebase + tid; e < eend; e += 1024) {
        int v = edge_v[e];
        int p = v / BINS;
        float2 g = f2v[e];
        int pos = atomicAdd(&cur[p], 1);
        if (pos < CAP)
            buckets[((size_t)b * PARTS + p) * CAP + pos] =
                make_uint2((unsigned)(v - p * BINS), pack_h2(g.x, g.y));
        else {
            atomicAdd(&out_vb_raw[2 * v + 0], g.x);
            atomicAdd(&out_vb_raw[2 * v + 1], g.y);
        }
    }
    __syncthreads();
    if (tid < PARTS) counts[b * PARTS + tid] = min(cur[tid], CAP);
}

// ---------------------------------------------------------------------------
// ACC2: accumulate -> clamp -> out_vb (f32 output) + accN (clamped half2 for k_fb)
__global__ __launch_bounds__(1024)
void k_acc2(const uint2* __restrict__ buckets,
            const int* __restrict__ counts,
            const unsigned short* __restrict__ vb_mask2,
            float2* __restrict__ out_vb,
            __half2* __restrict__ accN) {
    __shared__ float2 acc[BINS];
    __shared__ int pre[NBLK + 1];
    int p = blockIdx.x, tid = threadIdx.x;
    int vbase = p * BINS;
    int nb = min(BINS, V_ - vbase);

    for (int j = tid; j < BINS; j += 1024)
        acc[j] = (j < nb) ? out_vb[vbase + j] : make_float2(0.f, 0.f);
    if (tid < NBLK) pre[tid + 1] = counts[tid * PARTS + p];
    if (tid == 0) pre[0] = 0;
    __syncthreads();
#pragma unroll
    for (int off = 1; off < NBLK; off <<= 1) {
        int t = (tid >= off && tid < NBLK) ? pre[tid + 1 - off] : 0;
        __syncthreads();
        if (tid < NBLK) pre[tid + 1] += t;
        __syncthreads();
    }
    int T = pre[NBLK];
    for (int i = tid; i < T; i += 1024) {
        int lo = 0, hi = NBLK;
        while (hi - lo > 1) { int mid = (lo + hi) >> 1; if (pre[mid] <= i) lo = mid; else hi = mid; }
        uint2 pr = buckets[((size_t)lo * PARTS + p) * CAP + (i - pre[lo])];
        float2 mv = unpack_h2(pr.y);
        atomicAdd(&acc[pr.x].x, mv.x);
        atomicAdd(&acc[pr.x].y, mv.y);
    }
    __syncthreads();
    for (int j = tid; j < nb; j += 1024) {
        int v = vbase + j;
        unsigned short vbm = vb_mask2[v];
        float b0 = fmaxf((vbm & 0xff) ? LN_ZERO : acc[j].x, LN_ZERO);
        float b1 = fmaxf((vbm >> 8)   ? LN_ZERO : acc[j].y, LN_ZERO);
        out_vb[v] = make_float2(b0, b1);
        accN[v] = __floats2half2_rn(b0, b1);
    }
}

// ---------------------------------------------------------------------------
// Edge-parallel factor beliefs: gathers clamped vb_new as half2 (4 B/edge).
__global__ void k_factor_beliefs(const float2* __restrict__ new_f2v,
                                 const __half2* __restrict__ accN,   // clamped new
                                 const int* __restrict__ edge_v,
                                 const float4* __restrict__ pot4,
                                 const unsigned short* __restrict__ potbits,
                                 const unsigned short* __restrict__ v2f_mask2,
                                 float4* __restrict__ out_fb4) {
    int e = blockIdx.x * blockDim.x + threadIdx.x;
    if (e >= E_) return;
    int d = e & 3;

    float2 b = __half22float2(accN[edge_v[e]]);
    float2 g = new_f2v[e];
    unsigned short vm = v2f_mask2[e];
    float wx = fmaxf((vm & 0xff) ? LN_ZERO : (b.x - g.x), LN_ZERO);
    float wy = fmaxf((vm >> 8)   ? LN_ZERO : (b.y - g.y), LN_ZERO);

    float w0x = __shfl(wx, 0, 4), w0y = __shfl(wy, 0, 4);
    float w1x = __shfl(wx, 1, 4), w1y = __shfl(wy, 1, 4);
    float w2x = __shfl(wx, 2, 4), w2y = __shfl(wy, 2, 4);
    float w3x = __shfl(wx, 3, 4), w3y = __shfl(wy, 3, 4);

    float4 p = pot4[e];
    unsigned int pb = potbits[e >> 2] >> (4 * d);
    float A = ((d >> 1) ? w0y : w0x) + ((d & 1) ? w1y : w1x);
    float o0 = fmaxf((pb & 1u) ? LN_ZERO : (p.x + A + w2x + w3x), LN_ZERO);
    float o1 = fmaxf((pb & 2u) ? LN_ZERO : (p.y + A + w2x + w3y), LN_ZERO);
    float o2 = fmaxf((pb & 4u) ? LN_ZERO : (p.z + A + w2y + w3x), LN_ZERO);
    float o3 = fmaxf((pb & 8u) ? LN_ZERO : (p.w + A + w2y + w3y), LN_ZERO);
    out_fb4[e] = make_float4(o0, o1, o2, o3);
}

// ---------------------------------------------------------------------------
extern "C" void kernel_launch(void* const* d_in, const int* in_sizes, int n_in,
                              void* d_out, int out_size, void* d_ws, size_t ws_size,
                              hipStream_t stream) {
    const float* msgs     = (const float*)d_in[0];           // [E, C]
    const float* pot      = (const float*)d_in[1];           // [F, 16]
    const int*   edge_idx = (const int*)d_in[2];             // [2, E]
    const int*   pot_mask = (const int*)d_in[5];             // [F, 16] int32
    const unsigned char* f2v_mask = (const unsigned char*)d_in[6];  // [E, C]
    const unsigned char* v2f_mask = (const unsigned char*)d_in[7];  // [E, C]
    const unsigned char* vb_mask  = (const unsigned char*)d_in[8];  // [V, C]

    const int* edge_v = edge_idx + E_;

    float* out      = (float*)d_out;
    float* out_f2v  = out;                          // E*C floats
    float* out_vb   = out + (size_t)E_ * 2;         // V*C floats
    float* out_fb   = out_vb + (size_t)V_ * 2;      // F*16 floats = 16 MB

    // buckets live in the (dead until k_fb) out_fb region: 15.73 MB <= 16 MB
    uint2* buckets = (uint2*)out_fb;

    // workspace: counts + accP + accN + potbits  (~2.8 MB)
    int* counts = (int*)d_ws;                               // NBLK*PARTS ints
    __half2* accP = (__half2*)(counts + NBLK * PARTS);      // V half2
    __half2* accN = accP + V_;                              // V half2
    unsigned short* potbits = (unsigned short*)(accN + V_); // F ushort

    hipMemsetAsync(accP, 0, (size_t)V_ * sizeof(__half2), stream);
    hipMemsetAsync(out_vb, 0, (size_t)V_ * 2 * sizeof(float), stream);

    const int B = 256;
    dim3 gE((E_ + B - 1) / B);

    // crossing #1: msgs -> vb_prv (clamped half2 in accP)
    k_ms1<<<NBLK, 1024, 0, stream>>>(edge_v, (const float2*)msgs,
                                     (const int4*)pot_mask, potbits,
                                     buckets, counts, accP);
    k_acc1<<<PARTS, 1024, 0, stream>>>(buckets, counts,
                                       (const unsigned short*)vb_mask, accP);

    // factor messages (atomic-free)
    k_factor_msgs<<<gE, B, 0, stream>>>((const float2*)msgs, edge_v, accP,
                                        (const float4*)pot, potbits,
                                        (const unsigned short*)f2v_mask,
                                        (const unsigned short*)v2f_mask,
                                        (float2*)out_f2v);

    // crossing #2: new_f2v -> vb_new (clamped f32 in out_vb, half2 in accN)
    k_ms2<<<NBLK, 1024, 0, stream>>>(edge_v, (const float2*)out_f2v,
                                     buckets, counts, out_vb);
    k_acc2<<<PARTS, 1024, 0, stream>>>(buckets, counts,
                                       (const unsigned short*)vb_mask,
                                       (float2*)out_vb, accN);

    // factor beliefs (overwrites the bucket region with the real output)
    k_factor_beliefs<<<gE, B, 0, stream>>>((const float2*)out_f2v, accN, edge_v,
                                           (const float4*)pot, potbits,
                                           (const unsigned short*)v2f_mask,
                                           (float4*)out_fb);
}